// Round 16
// baseline (113.006 us; speedup 1.0000x reference)
//
#include <hip/hip_runtime.h>
#include <hip/hip_bf16.h>
#include <math.h>

// Problem constants (from reference): B=2, S=2048, D_MODEL=1024, H=16, D_K=64
#define SS 2048

typedef __attribute__((ext_vector_type(8))) __bf16 bf16x8;
typedef __attribute__((ext_vector_type(4))) float f32x4;
typedef __attribute__((ext_vector_type(16))) float f32x16;
typedef __attribute__((ext_vector_type(4))) unsigned int u32x4;
typedef __attribute__((ext_vector_type(4))) unsigned short u16x4;

__device__ __forceinline__ f32x4 mfma16(bf16x8 a, bf16x8 b, f32x4 c) {
  return __builtin_amdgcn_mfma_f32_16x16x32_bf16(a, b, c, 0, 0, 0);
}
__device__ __forceinline__ f32x16 mfma32(bf16x8 a, bf16x8 b, f32x16 c) {
  return __builtin_amdgcn_mfma_f32_32x32x16_bf16(a, b, c, 0, 0, 0);
}

__device__ __forceinline__ void gld_lds16(const void* g, void* l) {
  __builtin_amdgcn_global_load_lds(
      (__attribute__((address_space(1))) void*)(g),
      (__attribute__((address_space(3))) void*)(l), 16, 0, 0);
}

#if __has_builtin(__builtin_amdgcn_exp2f)
#define EXP2F(x) __builtin_amdgcn_exp2f(x)
#else
#define EXP2F(x) __expf(0.69314718056f * (x))
#endif

__device__ __forceinline__ unsigned int cvtpk_bf16(float lo, float hi) {
  unsigned int r;
  asm("v_cvt_pk_bf16_f32 %0, %1, %2" : "=v"(r) : "v"(lo), "v"(hi));
  return r;
}
__device__ __forceinline__ void swap32(unsigned int& x, unsigned int& y) {
  asm("v_permlane32_swap_b32 %0, %1" : "+v"(x), "+v"(y));
}
__device__ __forceinline__ unsigned short bfu(float v) {
  __bf16 h = (__bf16)v;
  return __builtin_bit_cast(unsigned short, h);
}

// ---------- fused: f32->bf16 converts (x, Wq..Wo) + trig table ----------
__global__ void prep_kernel(const float* __restrict__ x, const float* __restrict__ Wq,
                            const float* __restrict__ Wk, const float* __restrict__ Wv,
                            const float* __restrict__ Wo, const int* __restrict__ pos,
                            __bf16* __restrict__ xb, __bf16* __restrict__ Wb,
                            float2* __restrict__ tab) {
  const int bid = blockIdx.x, tid = threadIdx.x;
  if (bid >= 4096) {  // trig table
    int i = (bid - 4096) * 256 + tid;
    int s = i >> 5, j = i & 31;
    float p = (float)pos[s];
    float inv = exp2f((float)j * -0.41524101186098283f);  // -(2/64)*log2(10000)
    float f = p * inv;
    float sn, cs;
    sincosf(f, &sn, &cs);
    tab[i] = make_float2(cs, sn);
    return;
  }
  const float* s;
  __bf16* d;
  size_t base;
  if (bid < 2048) { s = x; d = xb; base = bid; }
  else {
    int seg = (bid - 2048) >> 9;
    s = (seg == 0) ? Wq : (seg == 1) ? Wk : (seg == 2) ? Wv : Wo;
    d = Wb + (size_t)seg * 1024 * 1024;
    base = (bid - 2048) & 511;
  }
  size_t i = (base * 256 + tid) * 8;
  float4 a = *reinterpret_cast<const float4*>(s + i);
  float4 b = *reinterpret_cast<const float4*>(s + i + 4);
  bf16x8 o;
  o[0] = (__bf16)a.x; o[1] = (__bf16)a.y; o[2] = (__bf16)a.z; o[3] = (__bf16)a.w;
  o[4] = (__bf16)b.x; o[5] = (__bf16)b.y; o[6] = (__bf16)b.z; o[7] = (__bf16)b.w;
  *reinterpret_cast<bf16x8*>(d + i) = o;
}

// ---------- 256x192 QKV GEMM: counted-vmcnt pipeline, grid 256 (1/CU) ----------
__global__ __launch_bounds__(512, 1) void gemm256_kernel(
    const __bf16* __restrict__ A, const __bf16* __restrict__ Bw,
    __bf16* __restrict__ C, __bf16* __restrict__ Vt,
    const float2* __restrict__ tab) {
  const int K = 1024, N = 3072, nk = 32;
  __shared__ __align__(16) __bf16 sm[57344];  // 112 KiB
  __bf16* lsA = sm;            // 4 slots x 8192 elems
  __bf16* lsB = sm + 32768;    // 4 slots x 6144 elems

  const int tid = threadIdx.x;
  const int lane = tid & 63;
  const int wave = tid >> 6;
  const int wr = wave >> 2, wc = wave & 3;  // 2M x 4N
  const bool lowW = wave < 6;               // stages B

  const int xcd = blockIdx.x & 7;
  const int ii = blockIdx.x >> 3;  // 0..31
  const int m0 = (2 * xcd + (ii & 1)) * 256;
  const int n0 = (ii >> 1) * 192;

  const f32x4 fzero = {0.f, 0.f, 0.f, 0.f};
  f32x4 acc[8][3];
#pragma unroll
  for (int f = 0; f < 8; ++f)
#pragma unroll
    for (int g = 0; g < 3; ++g) acc[f][g] = fzero;

  const int arow0 = tid >> 2, ac = tid & 3;
  const __bf16* gA0 = A + (size_t)(m0 + arow0) * K + 8 * (ac ^ ((arow0 >> 1) & 3));
  const __bf16* gA1 = A + (size_t)(m0 + 128 + arow0) * K + 8 * (ac ^ (((arow0 + 128) >> 1) & 3));
  const int bid0 = tid, bid1 = tid + 384;
  const int br0 = bid0 >> 2, br1 = bid1 >> 2;
  const __bf16* gB0 = Bw + (size_t)(n0 + br0) * K + 8 * ((bid0 & 3) ^ ((br0 >> 1) & 3));
  const __bf16* gB1 = Bw + (size_t)(n0 + br1) * K + 8 * ((bid1 & 3) ^ ((br1 >> 1) & 3));

#define STAGE256(kt_)                                                \
  do {                                                               \
    const int kc_ = (kt_) & 3;                                       \
    const int ko_ = (kt_) * 32;                                      \
    gld_lds16(gA0 + ko_, lsA + kc_ * 8192 + tid * 8);                \
    gld_lds16(gA1 + ko_, lsA + kc_ * 8192 + 4096 + tid * 8);         \
    if (lowW) {                                                      \
      gld_lds16(gB0 + ko_, lsB + kc_ * 6144 + tid * 8);              \
      gld_lds16(gB1 + ko_, lsB + kc_ * 6144 + 3072 + tid * 8);       \
    }                                                                \
  } while (0)

  STAGE256(0);
  STAGE256(1);

  const int lrow = lane & 15, hi = lane >> 4;

#pragma unroll 1
  for (int kt = 0; kt < nk; ++kt) {
    const int ksA = (kt & 3) * 8192, ksB = (kt & 3) * 6144;
    if (kt + 2 < nk) {
      STAGE256(kt + 2);
      if (lowW) asm volatile("s_waitcnt vmcnt(8)" ::: "memory");
      else      asm volatile("s_waitcnt vmcnt(4)" ::: "memory");
    } else if (kt == nk - 2) {
      if (lowW) asm volatile("s_waitcnt vmcnt(4)" ::: "memory");
      else      asm volatile("s_waitcnt vmcnt(2)" ::: "memory");
    } else {
      asm volatile("s_waitcnt vmcnt(0)" ::: "memory");
    }
    __builtin_amdgcn_s_barrier();

    bf16x8 bfr[3];
#pragma unroll
    for (int g = 0; g < 3; ++g) {
      const int r = wc * 48 + g * 16 + lrow;
      bfr[g] = *reinterpret_cast<const bf16x8*>(
          lsB + ksB + r * 32 + ((hi ^ ((r >> 1) & 3)) * 8));
    }
    bf16x8 af[4];
#pragma unroll
    for (int f = 0; f < 4; ++f) {
      const int r = wr * 128 + f * 16 + lrow;
      af[f] = *reinterpret_cast<const bf16x8*>(
          lsA + ksA + r * 32 + ((hi ^ ((r >> 1) & 3)) * 8));
    }
    __builtin_amdgcn_s_setprio(1);
#pragma unroll
    for (int f = 0; f < 4; ++f)
#pragma unroll
      for (int g = 0; g < 3; ++g) acc[f][g] = mfma16(af[f], bfr[g], acc[f][g]);
    __builtin_amdgcn_s_setprio(0);
#pragma unroll
    for (int f = 0; f < 4; ++f) {
      const int r = wr * 128 + (f + 4) * 16 + lrow;
      af[f] = *reinterpret_cast<const bf16x8*>(
          lsA + ksA + r * 32 + ((hi ^ ((r >> 1) & 3)) * 8));
    }
    __builtin_amdgcn_s_setprio(1);
#pragma unroll
    for (int f = 0; f < 4; ++f)
#pragma unroll
      for (int g = 0; g < 3; ++g) acc[f + 4][g] = mfma16(af[f], bfr[g], acc[f + 4][g]);
    __builtin_amdgcn_s_setprio(0);
  }
#undef STAGE256

  const int crow = (lane >> 4) * 4, ccol = lane & 15;
  const int par = ccol & 1;
#pragma unroll
  for (int g = 0; g < 3; ++g) {
    const int cb = n0 + wc * 48 + g * 16;  // 16-aligned fragment base
    if (cb < 2048) {  // q,k columns: RoPE
      const int jj = ((cb + ccol) >> 1) & 31;
#pragma unroll
      for (int f = 0; f < 8; ++f) {
#pragma unroll
        for (int t = 0; t < 4; ++t) {
          const int r = m0 + wr * 128 + f * 16 + crow + t;
          const int s = r & (SS - 1);
          float2 cs = tab[(s << 5) | jj];
          float v = acc[f][g][t];
          float o = __shfl_xor(v, 1);
          float y = par ? fmaf(o, cs.y, v * cs.x) : fmaf(v, cs.x, -o * cs.y);
          C[(size_t)r * N + cb + ccol] = (__bf16)y;
        }
      }
    } else {  // V columns: write transposed into Vt[(b*16+h)*64+d][s]
      const int c = cb - 2048 + ccol;
      const int hh = c >> 6, dd = c & 63;
#pragma unroll
      for (int f = 0; f < 8; ++f) {
        const int r0 = m0 + wr * 128 + f * 16 + crow;
        const int bb = r0 >> 11, s0 = r0 & (SS - 1);
        u16x4 pk;
#pragma unroll
        for (int t = 0; t < 4; ++t) pk[t] = bfu(acc[f][g][t]);
        *reinterpret_cast<u16x4*>(Vt + ((size_t)(bb * 16 + hh) * 64 + dd) * SS + s0) = pk;
      }
    }
  }
}

// ---------- out-projection: 128x128 counted-vmcnt pipeline, grid 256 ----------
__global__ __launch_bounds__(512, 1) void gemm_out_kernel(
    const __bf16* __restrict__ A, const __bf16* __restrict__ Bw,
    float* __restrict__ C) {
  const int K = 1024, N = 1024, nk = 32;
  __shared__ __align__(16) __bf16 sm[32768];  // 64 KiB
  __bf16* lsA = sm;
  __bf16* lsB = sm + 16384;

  const int tid = threadIdx.x;
  const int lane = tid & 63;
  const int wave = tid >> 6;
  const int wr = wave >> 2, wc = wave & 3;

  const int xcd = blockIdx.x & 7;
  const int ii = blockIdx.x >> 3;  // 0..31
  const int m0 = (4 * xcd + (ii & 3)) * 128;
  const int n0 = (ii >> 2) * 128;

  const f32x4 fzero = {0.f, 0.f, 0.f, 0.f};
  f32x4 acc[4][2];
#pragma unroll
  for (int f = 0; f < 4; ++f)
#pragma unroll
    for (int g = 0; g < 2; ++g) acc[f][g] = fzero;

  const int srow = tid >> 2, sc = tid & 3;
  const int ssc = 8 * (sc ^ ((srow >> 1) & 3));
  const __bf16* gA = A + (size_t)(m0 + srow) * K + ssc;
  const __bf16* gB = Bw + (size_t)(n0 + srow) * K + ssc;

#define STAGEO(kt_)                                        \
  do {                                                     \
    const int kc_ = (kt_) & 3;                             \
    gld_lds16(gA + (kt_) * 32, lsA + kc_ * 4096 + tid * 8);\
    gld_lds16(gB + (kt_) * 32, lsB + kc_ * 4096 + tid * 8);\
  } while (0)

  STAGEO(0);
  STAGEO(1);

  const int lrow = lane & 15, hi = lane >> 4;

#pragma unroll 1
  for (int kt = 0; kt < nk; ++kt) {
    const int ks = (kt & 3) * 4096;
    if (kt + 2 < nk) {
      STAGEO(kt + 2);
      asm volatile("s_waitcnt vmcnt(4)" ::: "memory");
    } else if (kt == nk - 2) {
      asm volatile("s_waitcnt vmcnt(2)" ::: "memory");
    } else {
      asm volatile("s_waitcnt vmcnt(0)" ::: "memory");
    }
    __builtin_amdgcn_s_barrier();

    bf16x8 bfr[2], af[4];
#pragma unroll
    for (int g = 0; g < 2; ++g) {
      const int r = wc * 32 + g * 16 + lrow;
      bfr[g] = *reinterpret_cast<const bf16x8*>(
          lsB + ks + r * 32 + ((hi ^ ((r >> 1) & 3)) * 8));
    }
#pragma unroll
    for (int f = 0; f < 4; ++f) {
      const int r = wr * 64 + f * 16 + lrow;
      af[f] = *reinterpret_cast<const bf16x8*>(
          lsA + ks + r * 32 + ((hi ^ ((r >> 1) & 3)) * 8));
    }
    __builtin_amdgcn_s_setprio(1);
#pragma unroll
    for (int f = 0; f < 4; ++f)
#pragma unroll
      for (int g = 0; g < 2; ++g) acc[f][g] = mfma16(af[f], bfr[g], acc[f][g]);
    __builtin_amdgcn_s_setprio(0);
  }
#undef STAGEO

  const int crow = (lane >> 4) * 4, ccol = lane & 15;
#pragma unroll
  for (int f = 0; f < 4; ++f) {
#pragma unroll
    for (int g = 0; g < 2; ++g) {
      int r = m0 + wr * 64 + f * 16 + crow;
      int c = n0 + wc * 32 + g * 16 + ccol;
#pragma unroll
      for (int t = 0; t < 4; ++t) C[(size_t)(r + t) * N + c] = acc[f][g][t];
    }
  }
}

// ---------- causal flash attention: split-K + double-buffered pipeline ----------
// Fixed-shift softmax => KV-range partials exactly additive. SPLIT=1: grid
// 2048 (2 blocks per (b,h,qt), KV halves), 32 KB dbuf LDS, counted vmcnt(8)
// + raw barriers, 4 blocks/CU, all blocks <=16 rounds. XCD-pinned (b,h).
// BUGFIX vs R15: empty KV range (qt=0, half=1) must not issue the prologue
// STAGE (its in-flight loads raced the epilogue's LDS reuse); epilogue is
// now preceded by an unconditional vmcnt(0)+barrier.
#define CEXP 0.18033688011112042f  // log2(e)/8
#define SHIFT_B 16.0f

#define EXPSUM(S0, S1, L)                                                   \
  {                                                                         \
    float a0_ = 0.f, a1_ = 0.f, a2_ = 0.f, a3_ = 0.f;                       \
    _Pragma("unroll") for (int r = 0; r < 16; r += 4) {                     \
      S0[r] = EXP2F(fmaf(S0[r], CEXP, -SHIFT_B)); a0_ += S0[r];             \
      S0[r + 1] = EXP2F(fmaf(S0[r + 1], CEXP, -SHIFT_B)); a1_ += S0[r + 1]; \
      S0[r + 2] = EXP2F(fmaf(S0[r + 2], CEXP, -SHIFT_B)); a2_ += S0[r + 2]; \
      S0[r + 3] = EXP2F(fmaf(S0[r + 3], CEXP, -SHIFT_B)); a3_ += S0[r + 3]; \
    }                                                                       \
    _Pragma("unroll") for (int r = 0; r < 16; r += 4) {                     \
      S1[r] = EXP2F(fmaf(S1[r], CEXP, -SHIFT_B)); a0_ += S1[r];             \
      S1[r + 1] = EXP2F(fmaf(S1[r + 1], CEXP, -SHIFT_B)); a1_ += S1[r + 1]; \
      S1[r + 2] = EXP2F(fmaf(S1[r + 2], CEXP, -SHIFT_B)); a2_ += S1[r + 2]; \
      S1[r + 3] = EXP2F(fmaf(S1[r + 3], CEXP, -SHIFT_B)); a3_ += S1[r + 3]; \
    }                                                                       \
    float rs_ = (a0_ + a1_) + (a2_ + a3_);                                  \
    rs_ += __shfl_xor(rs_, 32);                                             \
    L += rs_;                                                               \
  }

template <int SPLIT>
__global__ __launch_bounds__(128) void attn_kernel(const __bf16* __restrict__ qkv,
                                                   const __bf16* __restrict__ Vt,
                                                   __bf16* __restrict__ pA,
                                                   __bf16* __restrict__ pB,
                                                   float* __restrict__ pL) {
  const int bid = blockIdx.x;
  // bid = t*8 + xcd; t = {[half(1b)] | g(2b) | phi(2b) | low(3b)}
  const int x = bid & 7, t8 = bid >> 3;
  const int low = t8 & 7, phi = (t8 >> 3) & 3, g = (t8 >> 5) & 3;
  const int half = SPLIT ? (t8 >> 7) : 0;
  const int hp = phi * 8 + x;  // (b,h) index 0..31, pinned to XCD x
  const int b = hp >> 4, h = hp & 15;
  const int qt = (g == 0) ? low : (g == 1) ? 31 - low : (g == 2) ? 15 - low : 16 + low;

  const int nkt = qt + 1;
  const int mid = (nkt + 1) >> 1;
  const int k0 = SPLIT ? (half ? mid : 0) : 0;
  const int k1 = SPLIT ? (half ? nkt : mid) : nkt;

  const int tid = threadIdx.x;
  const int wave = tid >> 6, lane = tid & 63;
  const int q32 = lane & 31, hi = lane >> 5;
  const int qw0 = qt * 64 + wave * 32;
  const int q = qw0 + q32;

  __shared__ __align__(16) __bf16 smem[16384];  // 32 KB: 2 slots x (K|V)

  bf16x8 qb[4];
  {
    const __bf16* qr = qkv + (size_t)(b * SS + q) * 3072 + h * 64;
#pragma unroll
    for (int slot = 0; slot < 4; ++slot)
      qb[slot] = *reinterpret_cast<const bf16x8*>(qr + slot * 16 + hi * 8);
  }
  asm volatile("s_waitcnt vmcnt(0)" ::: "memory");  // Q drained: clean counting

  const __bf16* kbase = qkv + (size_t)(b * SS) * 3072 + 1024 + h * 64;
  const __bf16* vbase = Vt + (size_t)((b * 16 + h) * 64) * SS;

  const int srow = tid >> 3, scg = tid & 7;
  const int ssc = 8 * (scg ^ (srow & 7));
  const __bf16* kG0 = kbase + (size_t)srow * 3072 + ssc;
  const __bf16* vG0 = vbase + (size_t)srow * SS + ssc;

#define STAGE(buf_, kt_)                                                      \
  do {                                                                        \
    const __bf16* kG = kG0 + (size_t)(kt_)*64 * 3072;                         \
    const __bf16* vG = vG0 + (size_t)(kt_)*64;                                \
    __bf16* sl_ = smem + (buf_)*8192;                                         \
    _Pragma("unroll") for (int u = 0; u < 4; ++u) {                           \
      gld_lds16(kG + (size_t)u * 16 * 3072, sl_ + tid * 8 + u * 1024);        \
      gld_lds16(vG + (size_t)u * 16 * SS, sl_ + 4096 + tid * 8 + u * 1024);   \
    }                                                                         \
  } while (0)

  const f32x16 fz16 = {0,0,0,0,0,0,0,0,0,0,0,0,0,0,0,0};
  f32x16 o0 = fz16, o1 = fz16;
  float lsum = 0.f;

  if (k0 < k1) STAGE(0, k0);  // 8 loads in flight (only if range non-empty)

#pragma unroll 1
  for (int kt = k0; kt < k1; ++kt) {
    const int buf = (kt - k0) & 1;
    if (kt + 1 < k1) {
      STAGE(buf ^ 1, kt + 1);  // 16 in flight; slot-kt = the 8 oldest
      asm volatile("s_waitcnt vmcnt(8)" ::: "memory");
    } else {
      asm volatile("s_waitcnt vmcnt(0)" ::: "memory");
    }
    __builtin_amdgcn_s_barrier();  // all waves' slot-kt loads landed

    const __bf16* lk = smem + buf * 8192;
    const __bf16* lv = lk + 4096;

    f32x16 s0 = fz16, s1 = fz16;
    __builtin_amdgcn_s_setprio(1);
#pragma unroll
    for (int slot = 0; slot < 4; ++slot) {
      const int swz = 8 * ((slot * 2 + hi) ^ (q32 & 7));
      bf16x8 kf0 = *reinterpret_cast<const bf16x8*>(lk + q32 * 64 + swz);
      bf16x8 kf1 = *reinterpret_cast<const bf16x8*>(lk + (32 + q32) * 64 + swz);
      s0 = mfma32(kf0, qb[slot], s0);
      s1 = mfma32(kf1, qb[slot], s1);
    }
    __builtin_amdgcn_s_setprio(0);

    if (kt == qt) {  // diagonal tile: causal mask
      const int kvb = kt * 64;
#pragma unroll
      for (int r = 0; r < 16; ++r) {
        const int rowc = (r & 3) + 8 * (r >> 2) + 4 * hi;
        if (kvb + rowc > q) s0[r] = -INFINITY;
        if (kvb + 32 + rowc > q) s1[r] = -INFINITY;
      }
    }

    EXPSUM(s0, s1, lsum)

    bf16x8 pb[4];
    {
      unsigned int A = cvtpk_bf16(s0[0], s0[1]), B2 = cvtpk_bf16(s0[2], s0[3]);
      unsigned int C2 = cvtpk_bf16(s0[4], s0[5]), D2 = cvtpk_bf16(s0[6], s0[7]);
      swap32(A, C2); swap32(B2, D2);
      u32x4 t0 = {A, B2, C2, D2};
      pb[0] = __builtin_bit_cast(bf16x8, t0);
      unsigned int E = cvtpk_bf16(s0[8], s0[9]), F = cvtpk_bf16(s0[10], s0[11]);
      unsigned int G = cvtpk_bf16(s0[12], s0[13]), H = cvtpk_bf16(s0[14], s0[15]);
      swap32(E, G); swap32(F, H);
      u32x4 t1 = {E, F, G, H};
      pb[1] = __builtin_bit_cast(bf16x8, t1);
      unsigned int A3 = cvtpk_bf16(s1[0], s1[1]), B3 = cvtpk_bf16(s1[2], s1[3]);
      unsigned int C3 = cvtpk_bf16(s1[4], s1[5]), D3 = cvtpk_bf16(s1[6], s1[7]);
      swap32(A3, C3); swap32(B3, D3);
      u32x4 t2 = {A3, B3, C3, D3};
      pb[2] = __builtin_bit_cast(bf16x8, t2);
      unsigned int E3 = cvtpk_bf16(s1[8], s1[9]), F3 = cvtpk_bf16(s1[10], s1[11]);
      unsigned int G3 = cvtpk_bf16(s1[12], s1[13]), H3 = cvtpk_bf16(s1[14], s1[15]);
      swap32(E3, G3); swap32(F3, H3);
      u32x4 t3 = {E3, F3, G3, H3};
      pb[3] = __builtin_bit_cast(bf16x8, t3);
    }

    __builtin_amdgcn_s_setprio(1);
#pragma unroll
    for (int slot = 0; slot < 4; ++slot) {
      const int swz = 8 * ((slot * 2 + hi) ^ (q32 & 7));
      bf16x8 v0 = *reinterpret_cast<const bf16x8*>(lv + q32 * 64 + swz);
      bf16x8 v1 = *reinterpret_cast<const bf16x8*>(lv + (32 + q32) * 64 + swz);
      o0 = mfma32(v0, pb[slot], o0);
      o1 = mfma32(v1, pb[slot], o1);
    }
    __builtin_amdgcn_s_setprio(0);

    __builtin_amdgcn_s_barrier();  // all waves done reading buf (skew bound)
  }

  // ---- epilogue: ensure no staged loads in flight, LDS free to reuse ----
  asm volatile("s_waitcnt vmcnt(0)" ::: "memory");
  __builtin_amdgcn_s_barrier();

  const float inv = SPLIT ? 1.0f : (1.0f / lsum);
  __bf16* ol = smem + wave * 2304;  // per-wave 32x72 region
#pragma unroll
  for (int r = 0; r < 16; ++r) {
    const int d = (r & 3) + 8 * (r >> 2) + 4 * hi;
    if (SPLIT) {
      ol[q32 * 72 + d] = (__bf16)o0[r];
      ol[q32 * 72 + 32 + d] = (__bf16)o1[r];
    } else {
      ol[q32 * 72 + d] = (__bf16)(o0[r] * inv);
      ol[q32 * 72 + 32 + d] = (__bf16)(o1[r] * inv);
    }
  }
  __bf16* dst = (SPLIT && half) ? pB : pA;
#pragma unroll
  for (int pass = 0; pass < 4; ++pass) {
    const int idx = pass * 64 + lane;
    const int row = idx >> 3, colc = idx & 7;
    bf16x8 v = *reinterpret_cast<const bf16x8*>(ol + row * 72 + colc * 8);
    *reinterpret_cast<bf16x8*>(
        dst + (size_t)(b * SS + qt * 64 + wave * 32 + row) * 1024 + h * 64 + colc * 8) = v;
  }
  if (SPLIT && hi == 0)
    pL[half * 65536 + hp * 2048 + qt * 64 + wave * 32 + q32] = lsum;
}

// ---------- combine: ao = (pA + pB) / (lA + lB) ----------
__global__ void combine_kernel(const __bf16* __restrict__ pB,
                               const float* __restrict__ pL,
                               __bf16* __restrict__ ao) {
  const int i = (blockIdx.x * 256 + threadIdx.x) * 8;  // over 4096*1024
  const int row = i >> 10, col = i & 1023;
  const int bb = row >> 11, s = row & 2047, h = col >> 6;
  const int bh = bb * 16 + h;
  const float lA = pL[bh * 2048 + s];
  const float lB = pL[65536 + bh * 2048 + s];
  const float inv = 1.0f / (lA + lB);
  bf16x8 a = *reinterpret_cast<const bf16x8*>(ao + i);
  bf16x8 b8 = *reinterpret_cast<const bf16x8*>(pB + i);
  bf16x8 o;
#pragma unroll
  for (int j = 0; j < 8; ++j) o[j] = (__bf16)(((float)a[j] + (float)b8[j]) * inv);
  *reinterpret_cast<bf16x8*>(ao + i) = o;
}

extern "C" void kernel_launch(void* const* d_in, const int* in_sizes, int n_in,
                              void* d_out, int out_size, void* d_ws, size_t ws_size,
                              hipStream_t stream) {
  const float* x  = (const float*)d_in[0];
  const int* pos  = (const int*)d_in[1];
  const float* Wq = (const float*)d_in[2];
  const float* Wk = (const float*)d_in[3];
  const float* Wv = (const float*)d_in[4];
  const float* Wo = (const float*)d_in[5];

  __bf16* xb  = (__bf16*)d_ws;                        // [4096][1024]    8 MB
  __bf16* Wb  = xb + (size_t)4096 * 1024;             // [4096][1024]    8 MB
  __bf16* qkv = Wb + (size_t)4096 * 1024;             // [4096][3072]   24 MB
  __bf16* Vt  = qkv + (size_t)4096 * 3072;            // [2048][2048]    8 MB
  __bf16* ao  = Vt + (size_t)2048 * 2048;             // [4096][1024]    8 MB (= pA)
  float2* tab = (float2*)(ao + (size_t)4096 * 1024);  // [2048*32]     0.5 MB
  __bf16* pB  = (__bf16*)(tab + 2048 * 32);           // [4096][1024]    8 MB
  float*  pL  = (float*)(pB + (size_t)4096 * 1024);   // [2][32][2048] 0.5 MB

  const size_t NEED = (size_t)(pL + 2 * 32 * 2048) - (size_t)d_ws;

  prep_kernel<<<4352, 256, 0, stream>>>(x, Wq, Wk, Wv, Wo, pos, xb, Wb, tab);
  gemm256_kernel<<<256, 512, 0, stream>>>(xb, Wb, qkv, Vt, tab);
  if (ws_size >= NEED) {
    attn_kernel<1><<<2048, 128, 0, stream>>>(qkv, Vt, ao, pB, pL);
    combine_kernel<<<2048, 256, 0, stream>>>(pB, pL, ao);
  } else {
    attn_kernel<0><<<1024, 128, 0, stream>>>(qkv, Vt, ao, nullptr, nullptr);
  }
  gemm_out_kernel<<<256, 512, 0, stream>>>(ao, Wb + (size_t)3 * 1024 * 1024, (float*)d_out);
}

// Round 17
// 100.316 us; speedup vs baseline: 1.1265x; 1.1265x over previous
//
#include <hip/hip_runtime.h>
#include <hip/hip_bf16.h>
#include <math.h>

// Problem constants (from reference): B=2, S=2048, D_MODEL=1024, H=16, D_K=64
#define SS 2048

typedef __attribute__((ext_vector_type(8))) __bf16 bf16x8;
typedef __attribute__((ext_vector_type(4))) float f32x4;
typedef __attribute__((ext_vector_type(16))) float f32x16;
typedef __attribute__((ext_vector_type(4))) unsigned int u32x4;
typedef __attribute__((ext_vector_type(4))) unsigned short u16x4;

__device__ __forceinline__ f32x4 mfma16(bf16x8 a, bf16x8 b, f32x4 c) {
  return __builtin_amdgcn_mfma_f32_16x16x32_bf16(a, b, c, 0, 0, 0);
}
__device__ __forceinline__ f32x16 mfma32(bf16x8 a, bf16x8 b, f32x16 c) {
  return __builtin_amdgcn_mfma_f32_32x32x16_bf16(a, b, c, 0, 0, 0);
}

__device__ __forceinline__ void gld_lds16(const void* g, void* l) {
  __builtin_amdgcn_global_load_lds(
      (__attribute__((address_space(1))) void*)(g),
      (__attribute__((address_space(3))) void*)(l), 16, 0, 0);
}

#if __has_builtin(__builtin_amdgcn_exp2f)
#define EXP2F(x) __builtin_amdgcn_exp2f(x)
#else
#define EXP2F(x) __expf(0.69314718056f * (x))
#endif

__device__ __forceinline__ unsigned int cvtpk_bf16(float lo, float hi) {
  unsigned int r;
  asm("v_cvt_pk_bf16_f32 %0, %1, %2" : "=v"(r) : "v"(lo), "v"(hi));
  return r;
}
__device__ __forceinline__ void swap32(unsigned int& x, unsigned int& y) {
  asm("v_permlane32_swap_b32 %0, %1" : "+v"(x), "+v"(y));
}
__device__ __forceinline__ unsigned short bfu(float v) {
  __bf16 h = (__bf16)v;
  return __builtin_bit_cast(unsigned short, h);
}

// ---------- fused: f32->bf16 converts (x, Wq..Wo) + trig table ----------
__global__ void prep_kernel(const float* __restrict__ x, const float* __restrict__ Wq,
                            const float* __restrict__ Wk, const float* __restrict__ Wv,
                            const float* __restrict__ Wo, const int* __restrict__ pos,
                            __bf16* __restrict__ xb, __bf16* __restrict__ Wb,
                            float2* __restrict__ tab) {
  const int bid = blockIdx.x, tid = threadIdx.x;
  if (bid >= 4096) {  // trig table
    int i = (bid - 4096) * 256 + tid;
    int s = i >> 5, j = i & 31;
    float p = (float)pos[s];
    float inv = exp2f((float)j * -0.41524101186098283f);  // -(2/64)*log2(10000)
    float f = p * inv;
    float sn, cs;
    sincosf(f, &sn, &cs);
    tab[i] = make_float2(cs, sn);
    return;
  }
  const float* s;
  __bf16* d;
  size_t base;
  if (bid < 2048) { s = x; d = xb; base = bid; }
  else {
    int seg = (bid - 2048) >> 9;
    s = (seg == 0) ? Wq : (seg == 1) ? Wk : (seg == 2) ? Wv : Wo;
    d = Wb + (size_t)seg * 1024 * 1024;
    base = (bid - 2048) & 511;
  }
  size_t i = (base * 256 + tid) * 8;
  float4 a = *reinterpret_cast<const float4*>(s + i);
  float4 b = *reinterpret_cast<const float4*>(s + i + 4);
  bf16x8 o;
  o[0] = (__bf16)a.x; o[1] = (__bf16)a.y; o[2] = (__bf16)a.z; o[3] = (__bf16)a.w;
  o[4] = (__bf16)b.x; o[5] = (__bf16)b.y; o[6] = (__bf16)b.z; o[7] = (__bf16)b.w;
  *reinterpret_cast<bf16x8*>(d + i) = o;
}

// ---------- 256x192 QKV GEMM: counted-vmcnt pipeline, grid 256 (1/CU) ----------
__global__ __launch_bounds__(512, 1) void gemm256_kernel(
    const __bf16* __restrict__ A, const __bf16* __restrict__ Bw,
    __bf16* __restrict__ C, __bf16* __restrict__ Vt,
    const float2* __restrict__ tab) {
  const int K = 1024, N = 3072, nk = 32;
  __shared__ __align__(16) __bf16 sm[57344];  // 112 KiB
  __bf16* lsA = sm;            // 4 slots x 8192 elems
  __bf16* lsB = sm + 32768;    // 4 slots x 6144 elems

  const int tid = threadIdx.x;
  const int lane = tid & 63;
  const int wave = tid >> 6;
  const int wr = wave >> 2, wc = wave & 3;  // 2M x 4N
  const bool lowW = wave < 6;               // stages B

  const int xcd = blockIdx.x & 7;
  const int ii = blockIdx.x >> 3;  // 0..31
  const int m0 = (2 * xcd + (ii & 1)) * 256;
  const int n0 = (ii >> 1) * 192;

  const f32x4 fzero = {0.f, 0.f, 0.f, 0.f};
  f32x4 acc[8][3];
#pragma unroll
  for (int f = 0; f < 8; ++f)
#pragma unroll
    for (int g = 0; g < 3; ++g) acc[f][g] = fzero;

  const int arow0 = tid >> 2, ac = tid & 3;
  const __bf16* gA0 = A + (size_t)(m0 + arow0) * K + 8 * (ac ^ ((arow0 >> 1) & 3));
  const __bf16* gA1 = A + (size_t)(m0 + 128 + arow0) * K + 8 * (ac ^ (((arow0 + 128) >> 1) & 3));
  const int bid0 = tid, bid1 = tid + 384;
  const int br0 = bid0 >> 2, br1 = bid1 >> 2;
  const __bf16* gB0 = Bw + (size_t)(n0 + br0) * K + 8 * ((bid0 & 3) ^ ((br0 >> 1) & 3));
  const __bf16* gB1 = Bw + (size_t)(n0 + br1) * K + 8 * ((bid1 & 3) ^ ((br1 >> 1) & 3));

#define STAGE256(kt_)                                                \
  do {                                                               \
    const int kc_ = (kt_) & 3;                                       \
    const int ko_ = (kt_) * 32;                                      \
    gld_lds16(gA0 + ko_, lsA + kc_ * 8192 + tid * 8);                \
    gld_lds16(gA1 + ko_, lsA + kc_ * 8192 + 4096 + tid * 8);         \
    if (lowW) {                                                      \
      gld_lds16(gB0 + ko_, lsB + kc_ * 6144 + tid * 8);              \
      gld_lds16(gB1 + ko_, lsB + kc_ * 6144 + 3072 + tid * 8);       \
    }                                                                \
  } while (0)

  STAGE256(0);
  STAGE256(1);

  const int lrow = lane & 15, hi = lane >> 4;

#pragma unroll 1
  for (int kt = 0; kt < nk; ++kt) {
    const int ksA = (kt & 3) * 8192, ksB = (kt & 3) * 6144;
    if (kt + 2 < nk) {
      STAGE256(kt + 2);
      if (lowW) asm volatile("s_waitcnt vmcnt(8)" ::: "memory");
      else      asm volatile("s_waitcnt vmcnt(4)" ::: "memory");
    } else if (kt == nk - 2) {
      if (lowW) asm volatile("s_waitcnt vmcnt(4)" ::: "memory");
      else      asm volatile("s_waitcnt vmcnt(2)" ::: "memory");
    } else {
      asm volatile("s_waitcnt vmcnt(0)" ::: "memory");
    }
    __builtin_amdgcn_s_barrier();

    bf16x8 bfr[3];
#pragma unroll
    for (int g = 0; g < 3; ++g) {
      const int r = wc * 48 + g * 16 + lrow;
      bfr[g] = *reinterpret_cast<const bf16x8*>(
          lsB + ksB + r * 32 + ((hi ^ ((r >> 1) & 3)) * 8));
    }
    bf16x8 af[4];
#pragma unroll
    for (int f = 0; f < 4; ++f) {
      const int r = wr * 128 + f * 16 + lrow;
      af[f] = *reinterpret_cast<const bf16x8*>(
          lsA + ksA + r * 32 + ((hi ^ ((r >> 1) & 3)) * 8));
    }
    __builtin_amdgcn_s_setprio(1);
#pragma unroll
    for (int f = 0; f < 4; ++f)
#pragma unroll
      for (int g = 0; g < 3; ++g) acc[f][g] = mfma16(af[f], bfr[g], acc[f][g]);
    __builtin_amdgcn_s_setprio(0);
#pragma unroll
    for (int f = 0; f < 4; ++f) {
      const int r = wr * 128 + (f + 4) * 16 + lrow;
      af[f] = *reinterpret_cast<const bf16x8*>(
          lsA + ksA + r * 32 + ((hi ^ ((r >> 1) & 3)) * 8));
    }
    __builtin_amdgcn_s_setprio(1);
#pragma unroll
    for (int f = 0; f < 4; ++f)
#pragma unroll
      for (int g = 0; g < 3; ++g) acc[f + 4][g] = mfma16(af[f], bfr[g], acc[f + 4][g]);
    __builtin_amdgcn_s_setprio(0);
  }
#undef STAGE256

  const int crow = (lane >> 4) * 4, ccol = lane & 15;
  const int par = ccol & 1;
#pragma unroll
  for (int g = 0; g < 3; ++g) {
    const int cb = n0 + wc * 48 + g * 16;  // 16-aligned fragment base
    if (cb < 2048) {  // q,k columns: RoPE
      const int jj = ((cb + ccol) >> 1) & 31;
#pragma unroll
      for (int f = 0; f < 8; ++f) {
#pragma unroll
        for (int t = 0; t < 4; ++t) {
          const int r = m0 + wr * 128 + f * 16 + crow + t;
          const int s = r & (SS - 1);
          float2 cs = tab[(s << 5) | jj];
          float v = acc[f][g][t];
          float o = __shfl_xor(v, 1);
          float y = par ? fmaf(o, cs.y, v * cs.x) : fmaf(v, cs.x, -o * cs.y);
          C[(size_t)r * N + cb + ccol] = (__bf16)y;
        }
      }
    } else {  // V columns: write transposed into Vt[(b*16+h)*64+d][s]
      const int c = cb - 2048 + ccol;
      const int hh = c >> 6, dd = c & 63;
#pragma unroll
      for (int f = 0; f < 8; ++f) {
        const int r0 = m0 + wr * 128 + f * 16 + crow;
        const int bb = r0 >> 11, s0 = r0 & (SS - 1);
        u16x4 pk;
#pragma unroll
        for (int t = 0; t < 4; ++t) pk[t] = bfu(acc[f][g][t]);
        *reinterpret_cast<u16x4*>(Vt + ((size_t)(bb * 16 + hh) * 64 + dd) * SS + s0) = pk;
      }
    }
  }
}

// ---------- out-projection: 128x128 counted-vmcnt pipeline, grid 256 ----------
__global__ __launch_bounds__(512, 1) void gemm_out_kernel(
    const __bf16* __restrict__ A, const __bf16* __restrict__ Bw,
    float* __restrict__ C) {
  const int K = 1024, N = 1024, nk = 32;
  __shared__ __align__(16) __bf16 sm[32768];  // 64 KiB
  __bf16* lsA = sm;
  __bf16* lsB = sm + 16384;

  const int tid = threadIdx.x;
  const int lane = tid & 63;
  const int wave = tid >> 6;
  const int wr = wave >> 2, wc = wave & 3;

  const int xcd = blockIdx.x & 7;
  const int ii = blockIdx.x >> 3;  // 0..31
  const int m0 = (4 * xcd + (ii & 3)) * 128;
  const int n0 = (ii >> 2) * 128;

  const f32x4 fzero = {0.f, 0.f, 0.f, 0.f};
  f32x4 acc[4][2];
#pragma unroll
  for (int f = 0; f < 4; ++f)
#pragma unroll
    for (int g = 0; g < 2; ++g) acc[f][g] = fzero;

  const int srow = tid >> 2, sc = tid & 3;
  const int ssc = 8 * (sc ^ ((srow >> 1) & 3));
  const __bf16* gA = A + (size_t)(m0 + srow) * K + ssc;
  const __bf16* gB = Bw + (size_t)(n0 + srow) * K + ssc;

#define STAGEO(kt_)                                        \
  do {                                                     \
    const int kc_ = (kt_) & 3;                             \
    gld_lds16(gA + (kt_) * 32, lsA + kc_ * 4096 + tid * 8);\
    gld_lds16(gB + (kt_) * 32, lsB + kc_ * 4096 + tid * 8);\
  } while (0)

  STAGEO(0);
  STAGEO(1);

  const int lrow = lane & 15, hi = lane >> 4;

#pragma unroll 1
  for (int kt = 0; kt < nk; ++kt) {
    const int ks = (kt & 3) * 4096;
    if (kt + 2 < nk) {
      STAGEO(kt + 2);
      asm volatile("s_waitcnt vmcnt(4)" ::: "memory");
    } else if (kt == nk - 2) {
      asm volatile("s_waitcnt vmcnt(2)" ::: "memory");
    } else {
      asm volatile("s_waitcnt vmcnt(0)" ::: "memory");
    }
    __builtin_amdgcn_s_barrier();

    bf16x8 bfr[2], af[4];
#pragma unroll
    for (int g = 0; g < 2; ++g) {
      const int r = wc * 32 + g * 16 + lrow;
      bfr[g] = *reinterpret_cast<const bf16x8*>(
          lsB + ks + r * 32 + ((hi ^ ((r >> 1) & 3)) * 8));
    }
#pragma unroll
    for (int f = 0; f < 4; ++f) {
      const int r = wr * 64 + f * 16 + lrow;
      af[f] = *reinterpret_cast<const bf16x8*>(
          lsA + ks + r * 32 + ((hi ^ ((r >> 1) & 3)) * 8));
    }
    __builtin_amdgcn_s_setprio(1);
#pragma unroll
    for (int f = 0; f < 4; ++f)
#pragma unroll
      for (int g = 0; g < 2; ++g) acc[f][g] = mfma16(af[f], bfr[g], acc[f][g]);
    __builtin_amdgcn_s_setprio(0);
  }
#undef STAGEO

  const int crow = (lane >> 4) * 4, ccol = lane & 15;
#pragma unroll
  for (int f = 0; f < 4; ++f) {
#pragma unroll
    for (int g = 0; g < 2; ++g) {
      int r = m0 + wr * 64 + f * 16 + crow;
      int c = n0 + wc * 32 + g * 16 + ccol;
#pragma unroll
      for (int t = 0; t < 4; ++t) C[(size_t)(r + t) * N + c] = acc[f][g][t];
    }
  }
}

// ---------- attention: uniform-length paired blocks ----------
#define CEXP 0.18033688011112042f  // log2(e)/8
#define SHIFT_B 16.0f

// one KV round: QK^T (swapped) -> fixed-shift exp+sum -> P->bf16 -> PV
__device__ __forceinline__ void attn_round(const __bf16* lk, const __bf16* lv,
                                           const bf16x8 (&qb)[4], f32x16& o0,
                                           f32x16& o1, float& lsum, int q,
                                           int kvb, bool diag, int q32, int hi) {
  const f32x16 fz16 = {0,0,0,0,0,0,0,0,0,0,0,0,0,0,0,0};
  f32x16 s0 = fz16, s1 = fz16;
  __builtin_amdgcn_s_setprio(1);
#pragma unroll
  for (int slot = 0; slot < 4; ++slot) {
    const int swz = 8 * ((slot * 2 + hi) ^ (q32 & 7));
    bf16x8 kf0 = *reinterpret_cast<const bf16x8*>(lk + q32 * 64 + swz);
    bf16x8 kf1 = *reinterpret_cast<const bf16x8*>(lk + (32 + q32) * 64 + swz);
    s0 = mfma32(kf0, qb[slot], s0);
    s1 = mfma32(kf1, qb[slot], s1);
  }
  __builtin_amdgcn_s_setprio(0);

  if (diag) {
#pragma unroll
    for (int r = 0; r < 16; ++r) {
      const int rowc = (r & 3) + 8 * (r >> 2) + 4 * hi;
      if (kvb + rowc > q) s0[r] = -INFINITY;
      if (kvb + 32 + rowc > q) s1[r] = -INFINITY;
    }
  }

  {
    float a0 = 0.f, a1 = 0.f, a2 = 0.f, a3 = 0.f;
#pragma unroll
    for (int r = 0; r < 16; r += 4) {
      s0[r] = EXP2F(fmaf(s0[r], CEXP, -SHIFT_B)); a0 += s0[r];
      s0[r + 1] = EXP2F(fmaf(s0[r + 1], CEXP, -SHIFT_B)); a1 += s0[r + 1];
      s0[r + 2] = EXP2F(fmaf(s0[r + 2], CEXP, -SHIFT_B)); a2 += s0[r + 2];
      s0[r + 3] = EXP2F(fmaf(s0[r + 3], CEXP, -SHIFT_B)); a3 += s0[r + 3];
    }
#pragma unroll
    for (int r = 0; r < 16; r += 4) {
      s1[r] = EXP2F(fmaf(s1[r], CEXP, -SHIFT_B)); a0 += s1[r];
      s1[r + 1] = EXP2F(fmaf(s1[r + 1], CEXP, -SHIFT_B)); a1 += s1[r + 1];
      s1[r + 2] = EXP2F(fmaf(s1[r + 2], CEXP, -SHIFT_B)); a2 += s1[r + 2];
      s1[r + 3] = EXP2F(fmaf(s1[r + 3], CEXP, -SHIFT_B)); a3 += s1[r + 3];
    }
    float rs = (a0 + a1) + (a2 + a3);
    rs += __shfl_xor(rs, 32);
    lsum += rs;
  }

  bf16x8 pb[4];
  {
    unsigned int A = cvtpk_bf16(s0[0], s0[1]), B2 = cvtpk_bf16(s0[2], s0[3]);
    unsigned int C2 = cvtpk_bf16(s0[4], s0[5]), D2 = cvtpk_bf16(s0[6], s0[7]);
    swap32(A, C2); swap32(B2, D2);
    u32x4 t0 = {A, B2, C2, D2};
    pb[0] = __builtin_bit_cast(bf16x8, t0);
    unsigned int E = cvtpk_bf16(s0[8], s0[9]), F = cvtpk_bf16(s0[10], s0[11]);
    unsigned int G = cvtpk_bf16(s0[12], s0[13]), H = cvtpk_bf16(s0[14], s0[15]);
    swap32(E, G); swap32(F, H);
    u32x4 t1 = {E, F, G, H};
    pb[1] = __builtin_bit_cast(bf16x8, t1);
    unsigned int A3 = cvtpk_bf16(s1[0], s1[1]), B3 = cvtpk_bf16(s1[2], s1[3]);
    unsigned int C3 = cvtpk_bf16(s1[4], s1[5]), D3 = cvtpk_bf16(s1[6], s1[7]);
    swap32(A3, C3); swap32(B3, D3);
    u32x4 t2 = {A3, B3, C3, D3};
    pb[2] = __builtin_bit_cast(bf16x8, t2);
    unsigned int E3 = cvtpk_bf16(s1[8], s1[9]), F3 = cvtpk_bf16(s1[10], s1[11]);
    unsigned int G3 = cvtpk_bf16(s1[12], s1[13]), H3 = cvtpk_bf16(s1[14], s1[15]);
    swap32(E3, G3); swap32(F3, H3);
    u32x4 t3 = {E3, F3, G3, H3};
    pb[3] = __builtin_bit_cast(bf16x8, t3);
  }

  __builtin_amdgcn_s_setprio(1);
#pragma unroll
  for (int slot = 0; slot < 4; ++slot) {
    const int swz = 8 * ((slot * 2 + hi) ^ (q32 & 7));
    bf16x8 v0 = *reinterpret_cast<const bf16x8*>(lv + q32 * 64 + swz);
    bf16x8 v1 = *reinterpret_cast<const bf16x8*>(lv + (32 + q32) * 64 + swz);
    o0 = mfma32(v0, pb[slot], o0);
    o1 = mfma32(v1, pb[slot], o1);
  }
  __builtin_amdgcn_s_setprio(0);
}

// Paired uniform blocks: block (bh, i, half); pair = (qtA=i, qtB=31-i).
// half0 = all of qtA (i+1 rounds) + first 16-i rounds of qtB = 17 rounds.
// half1 = last 16 rounds of qtB. Fixed-shift softmax => partials additive.
// qtA output final from half0 (no combine); qtB combined from ao-raw + pB.
// dbuf 32KB LDS, counted vmcnt(8), 4 blocks/CU, ALL blocks uniform length.
__global__ __launch_bounds__(128) void attn_pair_kernel(
    const __bf16* __restrict__ qkv, const __bf16* __restrict__ Vt,
    __bf16* __restrict__ AO, __bf16* __restrict__ pB, float* __restrict__ pL) {
  const int bid = blockIdx.x;
  // bid = t*8 + xcd; t = {half(1b) | i(4b) | phi(2b)}
  const int x = bid & 7, t7 = bid >> 3;
  const int phi = t7 & 3, pi = (t7 >> 2) & 15, half = t7 >> 6;
  const int hp = phi * 8 + x;  // (b,h) 0..31, pinned to XCD x
  const int b = hp >> 4, h = hp & 15;
  const int qtA = pi, qtB = 31 - pi;
  const int nr = half ? 16 : 17;
  const int segA = half ? 0 : (pi + 1);  // rounds belonging to qtA

  const int tid = threadIdx.x;
  const int wave = tid >> 6, lane = tid & 63;
  const int q32 = lane & 31, hi = lane >> 5;
  const int qA = qtA * 64 + wave * 32 + q32;
  const int qB = qtB * 64 + wave * 32 + q32;

  __shared__ __align__(16) __bf16 smem[16384];  // 32 KB: 2 slots x (K|V)

  bf16x8 qbA[4], qbB[4];
  {
    const __bf16* qrA = qkv + (size_t)(b * SS + qA) * 3072 + h * 64;
    const __bf16* qrB = qkv + (size_t)(b * SS + qB) * 3072 + h * 64;
#pragma unroll
    for (int slot = 0; slot < 4; ++slot) {
      qbA[slot] = *reinterpret_cast<const bf16x8*>(qrA + slot * 16 + hi * 8);
      qbB[slot] = *reinterpret_cast<const bf16x8*>(qrB + slot * 16 + hi * 8);
    }
  }
  asm volatile("s_waitcnt vmcnt(0)" ::: "memory");  // Q drained: clean counting

  const __bf16* kbase = qkv + (size_t)(b * SS) * 3072 + 1024 + h * 64;
  const __bf16* vbase = Vt + (size_t)((b * 16 + h) * 64) * SS;

  const int srow = tid >> 3, scg = tid & 7;
  const int ssc = 8 * (scg ^ (srow & 7));
  const __bf16* kG0 = kbase + (size_t)srow * 3072 + ssc;
  const __bf16* vG0 = vbase + (size_t)srow * SS + ssc;

  // round r -> KV tile index
#define KVOF(r_) (half ? (16 - pi + (r_)) : (((r_) < segA) ? (r_) : ((r_)-segA)))

#define STAGE(buf_, kv_)                                                      \
  do {                                                                        \
    const __bf16* kG = kG0 + (size_t)(kv_)*64 * 3072;                         \
    const __bf16* vG = vG0 + (size_t)(kv_)*64;                                \
    __bf16* sl_ = smem + (buf_)*8192;                                         \
    _Pragma("unroll") for (int u = 0; u < 4; ++u) {                           \
      gld_lds16(kG + (size_t)u * 16 * 3072, sl_ + tid * 8 + u * 1024);        \
      gld_lds16(vG + (size_t)u * 16 * SS, sl_ + 4096 + tid * 8 + u * 1024);   \
    }                                                                         \
  } while (0)

  const f32x16 fz16 = {0,0,0,0,0,0,0,0,0,0,0,0,0,0,0,0};
  f32x16 oA0 = fz16, oA1 = fz16, oB0 = fz16, oB1 = fz16;
  float lA = 0.f, lB = 0.f;

  STAGE(0, KVOF(0));

#pragma unroll 1
  for (int r = 0; r < nr; ++r) {
    const int buf = r & 1;
    if (r + 1 < nr) {
      STAGE(buf ^ 1, KVOF(r + 1));
      asm volatile("s_waitcnt vmcnt(8)" ::: "memory");
    } else {
      asm volatile("s_waitcnt vmcnt(0)" ::: "memory");
    }
    __builtin_amdgcn_s_barrier();

    const __bf16* lk = smem + buf * 8192;
    const __bf16* lv = lk + 4096;
    const int kv = KVOF(r);

    if (r < segA) {  // qtA segment (half0 only); wave-uniform branch
      attn_round(lk, lv, qbA, oA0, oA1, lA, qA, kv * 64, kv == qtA, q32, hi);
    } else {         // qtB segment
      attn_round(lk, lv, qbB, oB0, oB1, lB, qB, kv * 64, kv == qtB, q32, hi);
    }

    __builtin_amdgcn_s_barrier();  // all waves done reading buf (skew bound)
  }
#undef STAGE
#undef KVOF

  asm volatile("s_waitcnt vmcnt(0)" ::: "memory");
  __builtin_amdgcn_s_barrier();

  __bf16* ol = smem + wave * 2304;  // per-wave 32x72 region
  if (half == 0) {
    // ---- qtA rows: final output (divide in-kernel) ----
    const float invA = 1.0f / lA;
#pragma unroll
    for (int r = 0; r < 16; ++r) {
      const int d = (r & 3) + 8 * (r >> 2) + 4 * hi;
      ol[q32 * 72 + d] = (__bf16)(oA0[r] * invA);
      ol[q32 * 72 + 32 + d] = (__bf16)(oA1[r] * invA);
    }
#pragma unroll
    for (int pass = 0; pass < 4; ++pass) {
      const int idx = pass * 64 + lane;
      const int row = idx >> 3, colc = idx & 7;
      bf16x8 v = *reinterpret_cast<const bf16x8*>(ol + row * 72 + colc * 8);
      *reinterpret_cast<bf16x8*>(
          AO + (size_t)(b * SS + qtA * 64 + wave * 32 + row) * 1024 + h * 64 + colc * 8) = v;
    }
    // ---- qtB rows: raw partial into AO (in-wave LDS ordering suffices) ----
#pragma unroll
    for (int r = 0; r < 16; ++r) {
      const int d = (r & 3) + 8 * (r >> 2) + 4 * hi;
      ol[q32 * 72 + d] = (__bf16)oB0[r];
      ol[q32 * 72 + 32 + d] = (__bf16)oB1[r];
    }
#pragma unroll
    for (int pass = 0; pass < 4; ++pass) {
      const int idx = pass * 64 + lane;
      const int row = idx >> 3, colc = idx & 7;
      bf16x8 v = *reinterpret_cast<const bf16x8*>(ol + row * 72 + colc * 8);
      *reinterpret_cast<bf16x8*>(
          AO + (size_t)(b * SS + qtB * 64 + wave * 32 + row) * 1024 + h * 64 + colc * 8) = v;
    }
    if (hi == 0) pL[hp * 2048 + qtB * 64 + wave * 32 + q32] = lB;
  } else {
    // ---- qtB rows: raw partial into pB ----
#pragma unroll
    for (int r = 0; r < 16; ++r) {
      const int d = (r & 3) + 8 * (r >> 2) + 4 * hi;
      ol[q32 * 72 + d] = (__bf16)oB0[r];
      ol[q32 * 72 + 32 + d] = (__bf16)oB1[r];
    }
#pragma unroll
    for (int pass = 0; pass < 4; ++pass) {
      const int idx = pass * 64 + lane;
      const int row = idx >> 3, colc = idx & 7;
      bf16x8 v = *reinterpret_cast<const bf16x8*>(ol + row * 72 + colc * 8);
      *reinterpret_cast<bf16x8*>(
          pB + (size_t)(b * SS + qtB * 64 + wave * 32 + row) * 1024 + h * 64 + colc * 8) = v;
    }
    if (hi == 0) pL[65536 + hp * 2048 + qtB * 64 + wave * 32 + q32] = lB;
  }
}

// ---------- combine (qt >= 16 rows only): ao = (ao + pB) / (lA + lB) ----------
__global__ void combine_kernel(const __bf16* __restrict__ pB,
                               const float* __restrict__ pL,
                               __bf16* __restrict__ ao) {
  const int e = (blockIdx.x * 256 + threadIdx.x) * 8;  // over 2048*1024 subset
  const int subrow = e >> 10, col = e & 1023;
  const int bb = subrow >> 10, s = 1024 + (subrow & 1023);
  const int h = col >> 6;
  const int bh = bb * 16 + h;
  const size_t i = ((size_t)bb * SS + s) * 1024 + col;
  const float la = pL[bh * 2048 + s];
  const float lb = pL[65536 + bh * 2048 + s];
  const float inv = 1.0f / (la + lb);
  bf16x8 a = *reinterpret_cast<const bf16x8*>(ao + i);
  bf16x8 b8 = *reinterpret_cast<const bf16x8*>(pB + i);
  bf16x8 o;
#pragma unroll
  for (int j = 0; j < 8; ++j) o[j] = (__bf16)(((float)a[j] + (float)b8[j]) * inv);
  *reinterpret_cast<bf16x8*>(ao + i) = o;
}

extern "C" void kernel_launch(void* const* d_in, const int* in_sizes, int n_in,
                              void* d_out, int out_size, void* d_ws, size_t ws_size,
                              hipStream_t stream) {
  const float* x  = (const float*)d_in[0];
  const int* pos  = (const int*)d_in[1];
  const float* Wq = (const float*)d_in[2];
  const float* Wk = (const float*)d_in[3];
  const float* Wv = (const float*)d_in[4];
  const float* Wo = (const float*)d_in[5];

  __bf16* xb  = (__bf16*)d_ws;                        // [4096][1024]    8 MB
  __bf16* Wb  = xb + (size_t)4096 * 1024;             // [4096][1024]    8 MB
  __bf16* qkv = Wb + (size_t)4096 * 1024;             // [4096][3072]   24 MB
  __bf16* Vt  = qkv + (size_t)4096 * 3072;            // [2048][2048]    8 MB
  __bf16* ao  = Vt + (size_t)2048 * 2048;             // [4096][1024]    8 MB
  float2* tab = (float2*)(ao + (size_t)4096 * 1024);  // [2048*32]     0.5 MB
  __bf16* pB  = (__bf16*)(tab + 2048 * 32);           // [4096][1024]    8 MB
  float*  pL  = (float*)(pB + (size_t)4096 * 1024);   // [2][32][2048] 0.5 MB

  prep_kernel<<<4352, 256, 0, stream>>>(x, Wq, Wk, Wv, Wo, pos, xb, Wb, tab);
  gemm256_kernel<<<256, 512, 0, stream>>>(xb, Wb, qkv, Vt, tab);
  attn_pair_kernel<<<1024, 128, 0, stream>>>(qkv, Vt, ao, pB, pL);
  combine_kernel<<<1024, 256, 0, stream>>>(pB, pL, ao);
  gemm_out_kernel<<<256, 512, 0, stream>>>(ao, Wb + (size_t)3 * 1024 * 1024, (float*)d_out);
}